// Round 1
// baseline (346.073 us; speedup 1.0000x reference)
//
#include <hip/hip_runtime.h>
#include <hip/hip_bf16.h>

typedef __attribute__((ext_vector_type(8))) short bf16x8;
typedef __attribute__((ext_vector_type(4))) float f32x4;

#define NB 16
#define C 256
#define HH 56
#define WW 56
#define HW 3136
#define CHW 802816
#define NPIX 50176
#define PH 58
#define PW 58
#define KTOT 2304

// ---------------- kernel 1: BN stats (fp64) ----------------
__global__ void stats_kernel(const float* __restrict__ x, const float* __restrict__ gamma,
                             double* __restrict__ stats) {
  int c = blockIdx.x, tid = threadIdx.x;
  double s = 0.0, s2 = 0.0;
  const float* xc = x + (size_t)c * HW;
  for (int n = 0; n < NB; ++n) {
    const float* xb = xc + (size_t)n * CHW;
    for (int i = tid; i < HW; i += 256) { double v = (double)xb[i]; s += v; s2 += v * v; }
  }
  __shared__ double rs[256], rq[256];
  rs[tid] = s; rq[tid] = s2; __syncthreads();
  for (int o = 128; o > 0; o >>= 1) {
    if (tid < o) { rs[tid] += rs[tid + o]; rq[tid] += rq[tid + o]; }
    __syncthreads();
  }
  if (tid == 0) {
    double mean = rs[0] / (double)NPIX;
    double var = rq[0] / (double)NPIX - mean * mean;
    stats[c] = mean;
    stats[C + c] = (double)gamma[c] / sqrt(var + 1e-4);
  }
}

// ------- kernel 2: ternarize -> padded NHWC bf16 Tp + padded c_sum -------
__global__ void ternarize_kernel(const float* __restrict__ x, const float* __restrict__ beta,
                                 const double* __restrict__ stats,
                                 unsigned short* __restrict__ Tp, float* __restrict__ csum) {
  int bid = blockIdx.x, tid = threadIdx.x;
  int n = bid / HH, h = bid - n * HH;
  __shared__ unsigned short st[C][57];   // ternary bf16 bits, [c][w]
  __shared__ unsigned short sm[C][57];   // min(|xn|,1) fixed-point u16
  __shared__ float scs[WW];
  const float* xb = x + (size_t)n * CHW + h * WW;
  for (int idx = tid; idx < C * WW; idx += 256) {
    int c = idx / WW, w = idx - c * WW;
    double xn = ((double)xb[c * HW + w] - stats[c]) * stats[C + c] + (double)beta[c];
    st[c][w] = (xn > 0.0) ? 0x3F80u : 0xBF80u;
    float mf = (float)fmin(fabs(xn), 1.0);
    sm[c][w] = (unsigned short)(mf * 65535.0f + 0.5f);
  }
  __syncthreads();
  int lane = tid & 63, wid = tid >> 6;
  for (int w = wid; w < WW; w += 4) {
    float s = 0.f;
    for (int j = 0; j < 4; ++j) s += (float)sm[lane + 64 * j][w];
    s += __shfl_down(s, 32); s += __shfl_down(s, 16); s += __shfl_down(s, 8);
    s += __shfl_down(s, 4);  s += __shfl_down(s, 2);  s += __shfl_down(s, 1);
    if (lane == 0) scs[w] = s * (1.0f / 65535.0f);
  }
  __syncthreads();
  unsigned short* tb = Tp + ((size_t)(n * PH + h + 1) * PW + 1) * C;
  for (int idx = tid; idx < C * WW; idx += 256) {
    int c = idx & 255, w = idx >> 8;
    tb[w * C + c] = st[c][w];
  }
  if (tid < WW) csum[(size_t)(n * PH + h + 1) * PW + 1 + tid] = scs[tid];
}

// ------- kernel 3: weights OIHW -> [co][tap][c] bf16 (RNE) -------
__global__ void wprep_kernel(const float* __restrict__ cw, unsigned short* __restrict__ Wp) {
  int o = blockIdx.x * 256 + threadIdx.x;  // < 589824
  int co = o / KTOT, rr = o - co * KTOT;
  int tap = rr >> 8, c = rr & 255;
  float v = cw[co * KTOT + c * 9 + tap];
  unsigned u = __builtin_bit_cast(unsigned, v);
  unsigned lsb = (u >> 16) & 1u;
  u += 0x7FFFu + lsb;
  Wp[o] = (unsigned short)(u >> 16);
}

// ------- kernel 4: beta_map per pixel -------
__global__ void betamap_kernel(const float* __restrict__ csum, const float* __restrict__ betab,
                               float* __restrict__ bmap) {
  int idx = blockIdx.x * 256 + threadIdx.x;
  if (idx >= NPIX) return;
  int n = idx / HW, r = idx - n * HW;
  int h = r / WW, w = r - h * WW;
  const float* p = csum + (size_t)(n * PH + h) * PW + w;
  float s = 0.f;
  for (int i = 0; i < 3; ++i)
    for (int j = 0; j < 3; ++j) s += p[i * PW + j];
  int rows = 3 - (h == 0) - (h == HH - 1);
  int cols = 3 - (w == 0) - (w == WW - 1);
  float bb = betab[0];
  bmap[idx] = (s + bb) / (256.0f * (float)(rows * cols) + bb);
}

// ------- kernel 5: implicit-GEMM ternary conv, bf16 MFMA -------
__global__ __launch_bounds__(256) void conv_kernel(const unsigned short* __restrict__ Wp,
    const unsigned short* __restrict__ Tp, const float* __restrict__ convb,
    const float* __restrict__ bmap, float* __restrict__ out) {
  int bid = blockIdx.x;
  int pt = bid >> 1, ct = bid & 1;
  int pix0 = pt * 128, co0 = ct * 128;
  int tid = threadIdx.x;

  __shared__ __align__(16) unsigned short As[128 * 32];
  __shared__ __align__(16) unsigned short Bs[128 * 32];

  // staging addresses: thread -> (row = tid>>2, 16B segment = tid&3), rows r and r+64
  int arow = tid >> 2;
  int aseg = (tid & 3) * 8;
  const unsigned short* wA0 = Wp + (size_t)(co0 + arow) * KTOT + aseg;
  const unsigned short* wA1 = wA0 + (size_t)64 * KTOT;
  unsigned short* dA0 = As + arow * 32 + aseg;
  unsigned short* dA1 = dA0 + 64 * 32;
  int p0 = pix0 + arow;
  int n0 = p0 / HW; int r0 = p0 - n0 * HW; int h0 = r0 / WW; int w0 = r0 - h0 * WW;
  int p1 = p0 + 64;
  int n1 = p1 / HW; int r1 = p1 - n1 * HW; int h1 = r1 / WW; int w1 = r1 - h1 * WW;
  const unsigned short* tB0 = Tp + (size_t)((n0 * PH + h0) * PW + w0) * C + aseg;
  const unsigned short* tB1 = Tp + (size_t)((n1 * PH + h1) * PW + w1) * C + aseg;
  unsigned short* dB0 = Bs + arow * 32 + aseg;
  unsigned short* dB1 = dB0 + 64 * 32;

  int lane = tid & 63, wid = tid >> 6;
  int wm = (wid >> 1) * 64, wn = (wid & 1) * 64;
  int quad = lane >> 4, row16 = lane & 15;
  const unsigned short* aF = As + (wm + row16) * 32 + quad * 8;
  const unsigned short* bF = Bs + (wn + row16) * 32 + quad * 8;

  f32x4 acc[4][4];
  for (int mi = 0; mi < 4; ++mi)
    for (int ni = 0; ni < 4; ++ni)
      acc[mi][ni] = (f32x4){0.f, 0.f, 0.f, 0.f};

  for (int tap = 0; tap < 9; ++tap) {
    int kh = tap / 3, kw = tap - kh * 3;
    const unsigned short* wa0 = wA0 + tap * 256;
    const unsigned short* wa1 = wA1 + tap * 256;
    const unsigned short* tb0 = tB0 + (kh * PW + kw) * C;
    const unsigned short* tb1 = tB1 + (kh * PW + kw) * C;
    for (int c0 = 0; c0 < 256; c0 += 32) {
      __syncthreads();
      *(uint4*)dA0 = *(const uint4*)(wa0 + c0);
      *(uint4*)dA1 = *(const uint4*)(wa1 + c0);
      *(uint4*)dB0 = *(const uint4*)(tb0 + c0);
      *(uint4*)dB1 = *(const uint4*)(tb1 + c0);
      __syncthreads();
      bf16x8 a[4], b[4];
      for (int mi = 0; mi < 4; ++mi) a[mi] = *(const bf16x8*)(aF + mi * 512);
      for (int ni = 0; ni < 4; ++ni) b[ni] = *(const bf16x8*)(bF + ni * 512);
      for (int mi = 0; mi < 4; ++mi)
        for (int ni = 0; ni < 4; ++ni)
          acc[mi][ni] = __builtin_amdgcn_mfma_f32_16x16x32_bf16(a[mi], b[ni], acc[mi][ni], 0, 0, 0);
    }
  }

  // epilogue: out = (acc + conv_b) * beta_map
  for (int ni = 0; ni < 4; ++ni) {
    int p = pix0 + wn + ni * 16 + row16;
    int n = p / HW; int r = p - n * HW;
    float bm = bmap[p];
    float* ob = out + (size_t)n * CHW + r;
    for (int mi = 0; mi < 4; ++mi) {
      int co = co0 + wm + mi * 16 + quad * 4;
      for (int rg = 0; rg < 4; ++rg) {
        ob[(size_t)(co + rg) * HW] = (acc[mi][ni][rg] + convb[co + rg]) * bm;
      }
    }
  }
}

extern "C" void kernel_launch(void* const* d_in, const int* in_sizes, int n_in,
                              void* d_out, int out_size, void* d_ws, size_t ws_size,
                              hipStream_t stream) {
  const float* x     = (const float*)d_in[0];
  const float* gamma = (const float*)d_in[1];
  const float* beta  = (const float*)d_in[2];
  const float* convw = (const float*)d_in[3];
  const float* convb = (const float*)d_in[4];
  const float* betab = (const float*)d_in[5];
  float* out = (float*)d_out;

  char* ws = (char*)d_ws;
  unsigned short* Tp   = (unsigned short*)(ws);                 // 16*58*58*256*2 = 27,557,888
  unsigned short* Wp   = (unsigned short*)(ws + 27557888);      // 256*2304*2     =  1,179,648
  float*          csum = (float*)(ws + 28737536);               // 16*58*58*4     =    215,296
  float*          bmap = (float*)(ws + 28952832);               // 50176*4        =    200,704
  double*         stats= (double*)(ws + 29153536);              // 512*8          =      4,096

  hipMemsetAsync(Tp, 0, 27557888, stream);
  hipMemsetAsync(csum, 0, 215296, stream);

  stats_kernel<<<256, 256, 0, stream>>>(x, gamma, stats);
  wprep_kernel<<<2304, 256, 0, stream>>>(convw, Wp);
  ternarize_kernel<<<896, 256, 0, stream>>>(x, beta, stats, Tp, csum);
  betamap_kernel<<<196, 256, 0, stream>>>(csum, betab, bmap);
  conv_kernel<<<784, 256, 0, stream>>>(Wp, Tp, convb, bmap, out);
}

// Round 2
// 258.909 us; speedup vs baseline: 1.3367x; 1.3367x over previous
//
#include <hip/hip_runtime.h>
#include <hip/hip_bf16.h>

typedef __attribute__((ext_vector_type(8))) short bf16x8;
typedef __attribute__((ext_vector_type(4))) float f32x4;

#define NB 16
#define C 256
#define HH 56
#define WW 56
#define HW 3136
#define CHW 802816
#define NPIX 50176
#define PH 58
#define PW 58
#define KTOT 2304

#define GLL(g, l) __builtin_amdgcn_global_load_lds( \
    (const __attribute__((address_space(1))) void*)(g), \
    (__attribute__((address_space(3))) void*)(l), 16, 0, 0)

// ---------------- kernel 1: BN stats (fp64 accum, float4 loads) ----------------
__global__ void stats_kernel(const float* __restrict__ x, const float* __restrict__ gamma,
                             double* __restrict__ stats) {
  int c = blockIdx.x, tid = threadIdx.x;
  double s = 0.0, s2 = 0.0;
  const float* xc = x + (size_t)c * HW;
  for (int n = 0; n < NB; ++n) {
    const float4* xb = (const float4*)(xc + (size_t)n * CHW);
    for (int i = tid; i < HW / 4; i += 256) {
      float4 v = xb[i];
      double a = v.x, b = v.y, cc = v.z, d = v.w;
      s  += (a + b) + (cc + d);
      s2 += (a * a + b * b) + (cc * cc + d * d);
    }
  }
  __shared__ double rs[256], rq[256];
  rs[tid] = s; rq[tid] = s2; __syncthreads();
  for (int o = 128; o > 0; o >>= 1) {
    if (tid < o) { rs[tid] += rs[tid + o]; rq[tid] += rq[tid + o]; }
    __syncthreads();
  }
  if (tid == 0) {
    double mean = rs[0] / (double)NPIX;
    double var = rq[0] / (double)NPIX - mean * mean;
    stats[c] = mean;
    stats[C + c] = (double)gamma[c] / sqrt(var + 1e-4);
  }
}

// ------- kernel 2: ternarize -> padded NHWC bf16 Tp + padded c_sum -------
__global__ __launch_bounds__(256) void ternarize_kernel(const float* __restrict__ x,
                                 const float* __restrict__ beta,
                                 const double* __restrict__ stats,
                                 unsigned short* __restrict__ Tp, float* __restrict__ csum) {
  int bid = blockIdx.x, tid = threadIdx.x;
  int n = bid / HH, h = bid - n * HH;
  __shared__ unsigned short st2[56][256];  // [w][c] ternary bf16 bits
  __shared__ unsigned short sm2[56][256];  // [w][c] min(|xn|,1) u16 fixed-point
  const float* xb = x + (size_t)n * CHW + h * WW;
  for (int j = 0; j < 14; ++j) {
    int idx = tid + j * 256;               // < 3584 = 256c * 14q
    int c = idx / 14, q = idx - c * 14;
    float4 v = *(const float4*)(xb + (size_t)c * HW + q * 4);
    double mu = stats[c], sc = stats[C + c], bt = (double)beta[c];
    float vv[4] = {v.x, v.y, v.z, v.w};
#pragma unroll
    for (int e = 0; e < 4; ++e) {
      double xn = ((double)vv[e] - mu) * sc + bt;
      int w = q * 4 + e;
      st2[w][c] = (xn > 0.0) ? 0x3F80u : 0xBF80u;
      sm2[w][c] = (unsigned short)((float)fmin(fabs(xn), 1.0) * 65535.0f + 0.5f);
    }
  }
  __syncthreads();
  int lane = tid & 63, wid = tid >> 6;
  for (int w = wid; w < WW; w += 4) {
    ushort4 m4 = *(const ushort4*)(&sm2[w][lane * 4]);
    float s = (float)m4.x + (float)m4.y + (float)m4.z + (float)m4.w;
    s += __shfl_down(s, 32); s += __shfl_down(s, 16); s += __shfl_down(s, 8);
    s += __shfl_down(s, 4);  s += __shfl_down(s, 2);  s += __shfl_down(s, 1);
    if (lane == 0) csum[(size_t)(n * PH + h + 1) * PW + 1 + w] = s * (1.0f / 65535.0f);
  }
  // st2 is read-only after the first barrier; write pass
  unsigned short* tb = Tp + ((size_t)(n * PH + h + 1) * PW + 1) * C;
  for (int j = 0; j < 7; ++j) {
    int idx = tid + j * 256;               // < 1792 = 56w * 32
    int w = idx >> 5, c8 = idx & 31;
    *(uint4*)(tb + (size_t)w * C + c8 * 8) = *(const uint4*)(&st2[w][c8 * 8]);
  }
}

// ------- kernel 2b: zero the padded borders of Tp (replaces 27.5MB memset) -------
__global__ void border_kernel(unsigned short* __restrict__ Tp) {
  int g = blockIdx.x * 256 + threadIdx.x;  // 456*256 = 116736 = 16*228*32
  if (g >= 16 * 228 * 32) return;
  int n = g / 7296; int r = g - n * 7296;
  int pix = r >> 5, c8 = r & 31;
  int h, w;
  if (pix < 58)      { h = 0;  w = pix; }
  else if (pix < 116){ h = 57; w = pix - 58; }
  else { int rem = pix - 116; h = 1 + (rem >> 1); w = (rem & 1) ? 57 : 0; }
  uint4 z = {0u, 0u, 0u, 0u};
  *(uint4*)(Tp + (size_t)((n * PH + h) * PW + w) * C + c8 * 8) = z;
}

// ------- kernel 3: weights OIHW -> [co][tap][c] bf16 (RNE) -------
__global__ void wprep_kernel(const float* __restrict__ cw, unsigned short* __restrict__ Wp) {
  int o = blockIdx.x * 256 + threadIdx.x;  // < 589824
  int co = o / KTOT, rr = o - co * KTOT;
  int tap = rr >> 8, c = rr & 255;
  float v = cw[co * KTOT + c * 9 + tap];
  unsigned u = __builtin_bit_cast(unsigned, v);
  unsigned lsb = (u >> 16) & 1u;
  u += 0x7FFFu + lsb;
  Wp[o] = (unsigned short)(u >> 16);
}

// ------- kernel 4: beta_map per pixel -------
__global__ void betamap_kernel(const float* __restrict__ csum, const float* __restrict__ betab,
                               float* __restrict__ bmap) {
  int idx = blockIdx.x * 256 + threadIdx.x;
  if (idx >= NPIX) return;
  int n = idx / HW, r = idx - n * HW;
  int h = r / WW, w = r - h * WW;
  const float* p = csum + (size_t)(n * PH + h) * PW + w;
  float s = 0.f;
  for (int i = 0; i < 3; ++i)
    for (int j = 0; j < 3; ++j) s += p[i * PW + j];
  int rows = 3 - (h == 0) - (h == HH - 1);
  int cols = 3 - (w == 0) - (w == WW - 1);
  float bb = betab[0];
  bmap[idx] = (s + bb) / (256.0f * (float)(rows * cols) + bb);
}

// ------- kernel 5: implicit-GEMM ternary conv, bf16 MFMA + global_load_lds -------
__global__ __launch_bounds__(256) void conv_kernel(const unsigned short* __restrict__ Wp,
    const unsigned short* __restrict__ Tp, const float* __restrict__ convb,
    const float* __restrict__ bmap, float* __restrict__ out) {
  int bid = blockIdx.x;
  int pt = bid >> 1, ct = bid & 1;
  int pix0 = pt * 128, co0 = ct * 128;
  int tid = threadIdx.x;

  __shared__ __align__(16) unsigned short As[128 * 32];
  __shared__ __align__(16) unsigned short Bs[128 * 32];

  // staging: lane tid covers LDS bytes tid*16 (linear, as global_load_lds requires);
  // the XOR swizzle is applied on the GLOBAL segment: seg' = seg ^ ((row>>1)&3),
  // compensated at fragment-read time -> every b128 lands 2 lanes/bank (free).
  int arow = tid >> 2;                       // 0..63
  int aseg = tid & 3;
  int xseg = (aseg ^ ((arow >> 1) & 3)) * 8; // swizzled element offset within row
  const unsigned short* wA0 = Wp + (size_t)(co0 + arow) * KTOT + xseg;
  const unsigned short* wA1 = wA0 + (size_t)64 * KTOT;
  unsigned short* dA0 = As + tid * 8;        // byte offset tid*16
  unsigned short* dA1 = As + 2048 + tid * 8; // rows 64..127
  int p0 = pix0 + arow;
  int n0 = p0 / HW; int r0 = p0 - n0 * HW; int h0 = r0 / WW; int w0 = r0 - h0 * WW;
  int p1 = p0 + 64;
  int n1 = p1 / HW; int r1 = p1 - n1 * HW; int h1 = r1 / WW; int w1 = r1 - h1 * WW;
  const unsigned short* tB0 = Tp + (size_t)((n0 * PH + h0) * PW + w0) * C + xseg;
  const unsigned short* tB1 = Tp + (size_t)((n1 * PH + h1) * PW + w1) * C + xseg;
  unsigned short* dB0 = Bs + tid * 8;
  unsigned short* dB1 = Bs + 2048 + tid * 8;

  int lane = tid & 63, wid = tid >> 6;
  int wm = (wid >> 1) * 64, wn = (wid & 1) * 64;
  int quad = lane >> 4, row16 = lane & 15;
  int qsw = (quad ^ ((row16 >> 1) & 3)) * 8; // read-side swizzle compensation
  const unsigned short* aF = As + (wm + row16) * 32 + qsw;
  const unsigned short* bF = Bs + (wn + row16) * 32 + qsw;

  f32x4 acc[4][4];
  for (int mi = 0; mi < 4; ++mi)
    for (int ni = 0; ni < 4; ++ni)
      acc[mi][ni] = (f32x4){0.f, 0.f, 0.f, 0.f};

  for (int tap = 0; tap < 9; ++tap) {
    int kh = tap / 3, kw = tap - kh * 3;
    const unsigned short* wa0 = wA0 + tap * 256;
    const unsigned short* wa1 = wA1 + tap * 256;
    const unsigned short* tb0 = tB0 + (kh * PW + kw) * C;
    const unsigned short* tb1 = tB1 + (kh * PW + kw) * C;
#pragma unroll
    for (int c0 = 0; c0 < 256; c0 += 32) {
      __syncthreads();                       // prior chunk's reads complete
      GLL(wa0 + c0, dA0);
      GLL(wa1 + c0, dA1);
      GLL(tb0 + c0, dB0);
      GLL(tb1 + c0, dB1);
      __syncthreads();                       // drains vmcnt(0): LDS tiles ready
      bf16x8 a[4], b[4];
      for (int mi = 0; mi < 4; ++mi) a[mi] = *(const bf16x8*)(aF + mi * 512);
      for (int ni = 0; ni < 4; ++ni) b[ni] = *(const bf16x8*)(bF + ni * 512);
      for (int mi = 0; mi < 4; ++mi)
        for (int ni = 0; ni < 4; ++ni)
          acc[mi][ni] = __builtin_amdgcn_mfma_f32_16x16x32_bf16(a[mi], b[ni], acc[mi][ni], 0, 0, 0);
    }
  }

  // epilogue: out = (acc + conv_b) * beta_map
  for (int ni = 0; ni < 4; ++ni) {
    int p = pix0 + wn + ni * 16 + row16;
    int n = p / HW; int r = p - n * HW;
    float bm = bmap[p];
    float* ob = out + (size_t)n * CHW + r;
    for (int mi = 0; mi < 4; ++mi) {
      int co = co0 + wm + mi * 16 + quad * 4;
      for (int rg = 0; rg < 4; ++rg) {
        ob[(size_t)(co + rg) * HW] = (acc[mi][ni][rg] + convb[co + rg]) * bm;
      }
    }
  }
}

extern "C" void kernel_launch(void* const* d_in, const int* in_sizes, int n_in,
                              void* d_out, int out_size, void* d_ws, size_t ws_size,
                              hipStream_t stream) {
  const float* x     = (const float*)d_in[0];
  const float* gamma = (const float*)d_in[1];
  const float* beta  = (const float*)d_in[2];
  const float* convw = (const float*)d_in[3];
  const float* convb = (const float*)d_in[4];
  const float* betab = (const float*)d_in[5];
  float* out = (float*)d_out;

  char* ws = (char*)d_ws;
  unsigned short* Tp   = (unsigned short*)(ws);                 // 16*58*58*256*2 = 27,557,888
  unsigned short* Wp   = (unsigned short*)(ws + 27557888);      // 256*2304*2     =  1,179,648
  float*          csum = (float*)(ws + 28737536);               // 16*58*58*4     =    215,296
  float*          bmap = (float*)(ws + 28952832);               // 50176*4        =    200,704
  double*         stats= (double*)(ws + 29153536);              // 512*8          =      4,096

  hipMemsetAsync(csum, 0, 215296, stream);

  stats_kernel<<<256, 256, 0, stream>>>(x, gamma, stats);
  wprep_kernel<<<2304, 256, 0, stream>>>(convw, Wp);
  border_kernel<<<456, 256, 0, stream>>>(Tp);
  ternarize_kernel<<<896, 256, 0, stream>>>(x, beta, stats, Tp, csum);
  betamap_kernel<<<196, 256, 0, stream>>>(csum, betab, bmap);
  conv_kernel<<<784, 256, 0, stream>>>(Wp, Tp, convb, bmap, out);
}

// Round 3
// 225.729 us; speedup vs baseline: 1.5331x; 1.1470x over previous
//
#include <hip/hip_runtime.h>
#include <hip/hip_bf16.h>

typedef __attribute__((ext_vector_type(8))) short bf16x8;
typedef __attribute__((ext_vector_type(4))) float f32x4;

#define NB 16
#define C 256
#define HH 56
#define WW 56
#define HW 3136
#define CHW 802816
#define NPIX 50176
#define PH 58
#define PW 58
#define KTOT 2304

#define GLL(g, l) __builtin_amdgcn_global_load_lds( \
    (const __attribute__((address_space(1))) void*)(g), \
    (__attribute__((address_space(3))) void*)(l), 16, 0, 0)

// ---------------- kernel 1: BN stats (fp64 accum, float4 loads) ----------------
__global__ void stats_kernel(const float* __restrict__ x, const float* __restrict__ gamma,
                             double* __restrict__ stats) {
  int c = blockIdx.x, tid = threadIdx.x;
  double s = 0.0, s2 = 0.0;
  const float* xc = x + (size_t)c * HW;
  for (int n = 0; n < NB; ++n) {
    const float4* xb = (const float4*)(xc + (size_t)n * CHW);
    for (int i = tid; i < HW / 4; i += 256) {
      float4 v = xb[i];
      double a = v.x, b = v.y, cc = v.z, d = v.w;
      s  += (a + b) + (cc + d);
      s2 += (a * a + b * b) + (cc * cc + d * d);
    }
  }
  __shared__ double rs[256], rq[256];
  rs[tid] = s; rq[tid] = s2; __syncthreads();
  for (int o = 128; o > 0; o >>= 1) {
    if (tid < o) { rs[tid] += rs[tid + o]; rq[tid] += rq[tid + o]; }
    __syncthreads();
  }
  if (tid == 0) {
    double mean = rs[0] / (double)NPIX;
    double var = rq[0] / (double)NPIX - mean * mean;
    stats[c] = mean;
    stats[C + c] = (double)gamma[c] / sqrt(var + 1e-4);
  }
}

// ------- kernel 2: ternarize -> padded NHWC (channel-permuted) bf16 Tp + c_sum -------
// channel permutation: slot p = (c&31)*8 + (c>>5)  <->  c = (p&7)*32 + (p>>3)
__global__ __launch_bounds__(256) void ternarize_kernel(const float* __restrict__ x,
                                 const float* __restrict__ beta,
                                 const double* __restrict__ stats,
                                 unsigned short* __restrict__ Tp, float* __restrict__ csum) {
  int bid = blockIdx.x, tid = threadIdx.x;
  int n = bid / HH, h = bid - n * HH;
  __shared__ float xs[256][57];   // stride 57: transposed reads conflict-free (25 odd)
  const float* xb = x + (size_t)n * CHW + h * WW;
#pragma unroll
  for (int j = 0; j < 14; ++j) {
    int idx = j * 256 + tid;
    int c = idx / 14, q = idx - c * 14;
    float4 v = *(const float4*)(xb + (size_t)c * HW + q * 4);
    float* row = &xs[c][q * 4];
    row[0] = v.x; row[1] = v.y; row[2] = v.z; row[3] = v.w;
  }
  int c8 = tid & 31;
  double mu[8], sc[8], bt[8];
#pragma unroll
  for (int e = 0; e < 8; ++e) {
    int c = c8 + 32 * e;
    mu[e] = stats[c]; sc[e] = stats[C + c]; bt[e] = (double)beta[c];
  }
  __syncthreads();
  unsigned short* tb = Tp + ((size_t)(n * PH + h + 1) * PW + 1) * C;
  float* cs = csum + (size_t)(n * PH + h + 1) * PW + 1;
#pragma unroll
  for (int p = 0; p < 7; ++p) {
    int idx = p * 256 + tid;
    int w = idx >> 5;
    unsigned bits[4];
    float msum = 0.f;
#pragma unroll
    for (int e2 = 0; e2 < 4; ++e2) {
      unsigned lo, hi;
      {
        double xn = ((double)xs[c8 + 64 * e2][w] - mu[2 * e2]) * sc[2 * e2] + bt[2 * e2];
        lo = (xn > 0.0) ? 0x3F80u : 0xBF80u;
        msum += (float)fmin(fabs(xn), 1.0);
      }
      {
        double xn = ((double)xs[c8 + 64 * e2 + 32][w] - mu[2 * e2 + 1]) * sc[2 * e2 + 1] + bt[2 * e2 + 1];
        hi = (xn > 0.0) ? 0x3F80u : 0xBF80u;
        msum += (float)fmin(fabs(xn), 1.0);
      }
      bits[e2] = lo | (hi << 16);
    }
    msum += __shfl_xor(msum, 1); msum += __shfl_xor(msum, 2);
    msum += __shfl_xor(msum, 4); msum += __shfl_xor(msum, 8);
    msum += __shfl_xor(msum, 16);
    uint4 v4; v4.x = bits[0]; v4.y = bits[1]; v4.z = bits[2]; v4.w = bits[3];
    *(uint4*)(tb + (size_t)w * C + c8 * 8) = v4;
    if (c8 == 0) cs[w] = msum;
  }
}

// ------- kernel 2b: zero the padded borders of Tp (replaces 27.5MB memset) -------
__global__ void border_kernel(unsigned short* __restrict__ Tp) {
  int g = blockIdx.x * 256 + threadIdx.x;  // 456*256 >= 116736 = 16*228*32
  if (g >= 16 * 228 * 32) return;
  int n = g / 7296; int r = g - n * 7296;
  int pix = r >> 5, c8 = r & 31;
  int h, w;
  if (pix < 58)      { h = 0;  w = pix; }
  else if (pix < 116){ h = 57; w = pix - 58; }
  else { int rem = pix - 116; h = 1 + (rem >> 1); w = (rem & 1) ? 57 : 0; }
  uint4 z = {0u, 0u, 0u, 0u};
  *(uint4*)(Tp + (size_t)((n * PH + h) * PW + w) * C + c8 * 8) = z;
}

// ------- kernel 3: weights OIHW -> [co][tap][perm(c)] bf16 (RNE) -------
__global__ void wprep_kernel(const float* __restrict__ cw, unsigned short* __restrict__ Wp) {
  int o = blockIdx.x * 256 + threadIdx.x;  // < 589824
  int co = o / KTOT, rr = o - co * KTOT;
  int tap = rr >> 8, p = rr & 255;
  int c = (p & 7) * 32 + (p >> 3);         // inverse permutation
  float v = cw[co * KTOT + c * 9 + tap];
  unsigned u = __builtin_bit_cast(unsigned, v);
  unsigned lsb = (u >> 16) & 1u;
  u += 0x7FFFu + lsb;
  Wp[o] = (unsigned short)(u >> 16);
}

// ------- kernel 4: beta_map per pixel -------
__global__ void betamap_kernel(const float* __restrict__ csum, const float* __restrict__ betab,
                               float* __restrict__ bmap) {
  int idx = blockIdx.x * 256 + threadIdx.x;
  if (idx >= NPIX) return;
  int n = idx / HW, r = idx - n * HW;
  int h = r / WW, w = r - h * WW;
  const float* p = csum + (size_t)(n * PH + h) * PW + w;
  float s = 0.f;
  for (int i = 0; i < 3; ++i)
    for (int j = 0; j < 3; ++j) s += p[i * PW + j];
  int rows = 3 - (h == 0) - (h == HH - 1);
  int cols = 3 - (w == 0) - (w == WW - 1);
  float bb = betab[0];
  bmap[idx] = (s + bb) / (256.0f * (float)(rows * cols) + bb);
}

// ------- kernel 5: implicit-GEMM ternary conv, BK=64, global_load_lds, XOR-8 swizzle -------
__global__ __launch_bounds__(256) void conv_kernel(const unsigned short* __restrict__ Wp,
    const unsigned short* __restrict__ Tp, const float* __restrict__ convb,
    const float* __restrict__ bmap, float* __restrict__ out) {
  // XCD-aware swizzle: blocks g and g+8 (same XCD under b%8 mapping) share a pixel tile
  int g = blockIdx.x;
  int gg = g >> 3, xcd = g & 7;
  int ct = gg & 1;
  int pt = (gg >> 1) * 8 + xcd;
  int pix0 = pt * 128, co0 = ct * 128;
  int tid = threadIdx.x;

  __shared__ __align__(16) unsigned short As[128 * 64];  // 16 KB
  __shared__ __align__(16) unsigned short Bs[128 * 64];  // 16 KB

  // staging: LDS 16B-block L = 8*row + jj (linear in tid, as GLL requires);
  // global seg stored at slot jj is s = jj ^ (row&7)  (XOR-8 swizzle)
  int jj = tid & 7;
  int rr_ = tid >> 3;                       // 0..31
  int s = ((jj ^ (rr_ & 7)) * 8);           // element offset within 64-chunk

  const unsigned short* wA[4];
  const unsigned short* tB[4];
  unsigned short* dA[4];
  unsigned short* dB[4];
#pragma unroll
  for (int i = 0; i < 4; ++i) {
    int r = i * 32 + rr_;
    wA[i] = Wp + (size_t)(co0 + r) * KTOT + s;
    dA[i] = As + i * 2048 + tid * 8;
    int p = pix0 + r;
    int n = p / HW; int rm = p - n * HW; int h = rm / WW; int w = rm - h * WW;
    tB[i] = Tp + (size_t)((n * PH + h) * PW + w) * C + s;
    dB[i] = Bs + i * 2048 + tid * 8;
  }

  int lane = tid & 63, wid = tid >> 6;
  int wm = (wid >> 1) * 64, wn = (wid & 1) * 64;
  int quad = lane >> 4, row16 = lane & 15;
  int j0 = quad ^ (row16 & 7);              // physical seg for kk=0; kk=1 is j0^4
  const unsigned short* aB0 = As + (wm + row16) * 64 + j0 * 8;
  const unsigned short* aB1 = As + (wm + row16) * 64 + (j0 ^ 4) * 8;
  const unsigned short* bB0 = Bs + (wn + row16) * 64 + j0 * 8;
  const unsigned short* bB1 = Bs + (wn + row16) * 64 + (j0 ^ 4) * 8;

  f32x4 acc[4][4];
#pragma unroll
  for (int mi = 0; mi < 4; ++mi)
#pragma unroll
    for (int ni = 0; ni < 4; ++ni)
      acc[mi][ni] = (f32x4){0.f, 0.f, 0.f, 0.f};

  for (int tap = 0; tap < 9; ++tap) {
    int kh = tap / 3, kw = tap - kh * 3;
    size_t aoff = (size_t)tap * 256;
    size_t boff = (size_t)(kh * PW + kw) * C;
#pragma unroll
    for (int c0 = 0; c0 < 256; c0 += 64) {
      __syncthreads();
#pragma unroll
      for (int i = 0; i < 4; ++i) GLL(wA[i] + aoff + c0, dA[i]);
#pragma unroll
      for (int i = 0; i < 4; ++i) GLL(tB[i] + boff + c0, dB[i]);
      __syncthreads();
#pragma unroll
      for (int kk = 0; kk < 2; ++kk) {
        const unsigned short* ap = kk ? aB1 : aB0;
        const unsigned short* bp = kk ? bB1 : bB0;
        bf16x8 a[4], b[4];
#pragma unroll
        for (int mi = 0; mi < 4; ++mi) a[mi] = *(const bf16x8*)(ap + mi * 1024);
#pragma unroll
        for (int ni = 0; ni < 4; ++ni) b[ni] = *(const bf16x8*)(bp + ni * 1024);
#pragma unroll
        for (int mi = 0; mi < 4; ++mi)
#pragma unroll
          for (int ni = 0; ni < 4; ++ni)
            acc[mi][ni] = __builtin_amdgcn_mfma_f32_16x16x32_bf16(a[mi], b[ni], acc[mi][ni], 0, 0, 0);
      }
    }
  }

  // epilogue: out = (acc + conv_b) * beta_map
#pragma unroll
  for (int ni = 0; ni < 4; ++ni) {
    int p = pix0 + wn + ni * 16 + row16;
    int n = p / HW; int r = p - n * HW;
    float bm = bmap[p];
    float* ob = out + (size_t)n * CHW + r;
#pragma unroll
    for (int mi = 0; mi < 4; ++mi) {
      int co = co0 + wm + mi * 16 + quad * 4;
#pragma unroll
      for (int rg = 0; rg < 4; ++rg) {
        ob[(size_t)(co + rg) * HW] = (acc[mi][ni][rg] + convb[co + rg]) * bm;
      }
    }
  }
}

extern "C" void kernel_launch(void* const* d_in, const int* in_sizes, int n_in,
                              void* d_out, int out_size, void* d_ws, size_t ws_size,
                              hipStream_t stream) {
  const float* x     = (const float*)d_in[0];
  const float* gamma = (const float*)d_in[1];
  const float* beta  = (const float*)d_in[2];
  const float* convw = (const float*)d_in[3];
  const float* convb = (const float*)d_in[4];
  const float* betab = (const float*)d_in[5];
  float* out = (float*)d_out;

  char* ws = (char*)d_ws;
  unsigned short* Tp   = (unsigned short*)(ws);                 // 16*58*58*256*2 = 27,557,888
  unsigned short* Wp   = (unsigned short*)(ws + 27557888);      // 256*2304*2     =  1,179,648
  float*          csum = (float*)(ws + 28737536);               // 16*58*58*4     =    215,296
  float*          bmap = (float*)(ws + 28952832);               // 50176*4        =    200,704
  double*         stats= (double*)(ws + 29153536);              // 512*8          =      4,096

  hipMemsetAsync(csum, 0, 215296, stream);

  stats_kernel<<<256, 256, 0, stream>>>(x, gamma, stats);
  wprep_kernel<<<2304, 256, 0, stream>>>(convw, Wp);
  border_kernel<<<456, 256, 0, stream>>>(Tp);
  ternarize_kernel<<<896, 256, 0, stream>>>(x, beta, stats, Tp, csum);
  betamap_kernel<<<196, 256, 0, stream>>>(csum, betab, bmap);
  conv_kernel<<<784, 256, 0, stream>>>(Wp, Tp, convb, bmap, out);
}